// Round 1
// baseline (14743.439 us; speedup 1.0000x reference)
//
// pendulumRNNSA — 2-layer LSTM (B=256,T=512,H=256) + additive self-attention readout.
//
// Design (round 0):
//  * Attention readout does NOT feed the recurrence (future=0) -> defer it to
//    batched passes over all B*T rows; serial loop only runs the 2 LSTM cells.
//  * One block per batch row runs the full T-loop; h1/h2 in LDS, c1/c2 in regs;
//    no inter-block communication at all.
//  * LSTM weights pre-transposed+packed to bf16 (k-major, 2 rows x 2 k per 8B
//    load) -> streamed from L2 (resident per-XCD). fp32 accumulation.
//  * h2 and Y=tanh(h2@Wa1^T+ba1) stored bf16 in workspace; attention finished by
//    two GEMV-ish passes with Wa1/Wa2 staged in LDS (padded stride 258 ->
//    conflict-free ushort2 reads).
#include <hip/hip_runtime.h>
#include <hip/hip_bf16.h>

#define HD   256
#define TT   512
#define BB   256
#define G4H  1024

typedef unsigned short u16;
typedef unsigned int   u32;

__device__ __forceinline__ float bf2f(u16 v) { return __uint_as_float(((u32)v) << 16); }
__device__ __forceinline__ u16 f2bf(float f) {
    u32 u = __float_as_uint(f);
    u32 r = u + 0x7fffu + ((u >> 16) & 1u);   // RNE
    return (u16)(r >> 16);
}

// ---- prep: pack [4H][H] fp32 row-major -> bf16 [k/2][4H][2] so that thread u
// reads ushort4 {W[2u][2p], W[2u][2p+1], W[2u+1][2p], W[2u+1][2p+1]} at
// dst + p*2048 + 4u (coalesced 8B/lane).
__global__ void pack_w_kernel(const float* __restrict__ src, u16* __restrict__ dst) {
    int idx = blockIdx.x * 256 + threadIdx.x;   // 0..262143
    int r = idx >> 8;                           // gate row 0..1023
    int k = idx & 255;
    float v = src[idx];
    dst[(k >> 1) * 2048 + r * 2 + (k & 1)] = f2bf(v);
}

__global__ void cvt_bf_kernel(const float* __restrict__ src, u16* __restrict__ dst, int n) {
    int idx = blockIdx.x * 256 + threadIdx.x;
    if (idx < n) dst[idx] = f2bf(src[idx]);
}

__global__ void bias_kernel(const float* __restrict__ a1, const float* __restrict__ b1,
                            const float* __restrict__ a2, const float* __restrict__ b2,
                            float* __restrict__ o1, float* __restrict__ o2) {
    int i = blockIdx.x * 256 + threadIdx.x;     // grid 4 x 256 = 1024
    o1[i] = a1[i] + b1[i];
    o2[i] = a2[i] + b2[i];
}

// ---- recurrent core: one block per batch row, 512 threads (8 waves).
// Thread u computes gate rows {2u, 2u+1}; threads <256 do the cell updates.
__global__ __launch_bounds__(512) void lstm_kernel(
    const float* __restrict__ x,       // [B][T]
    const float* __restrict__ Wih1,    // [1024] (input size 1)
    const float* __restrict__ bias1,   // [1024] = b_ih1+b_hh1
    const float* __restrict__ bias2,   // [1024] = b_ih2+b_hh2
    const u16*  __restrict__ W1p,      // packed W_hh1
    const u16*  __restrict__ W2ip,     // packed W_ih2
    const u16*  __restrict__ W2hp,     // packed W_hh2
    u16*        __restrict__ H2out)    // [B*T][H] bf16
{
    __shared__ float sh1[HD], sh2[HD], g[G4H], xrow[TT];
    __shared__ float sWih1[G4H], sb1[G4H], sb2[G4H];
    const int b = blockIdx.x;
    const int u = threadIdx.x;          // 0..511

    for (int i = u; i < TT; i += 512) xrow[i] = x[b * TT + i];
    for (int i = u; i < G4H; i += 512) {
        sWih1[i] = Wih1[i]; sb1[i] = bias1[i]; sb2[i] = bias2[i];
    }
    if (u < HD) { sh1[u] = 0.f; sh2[u] = 0.f; }
    float c1 = 0.f, c2 = 0.f;
    __syncthreads();

    const u16* w1  = W1p  + 4 * u;
    const u16* w2i = W2ip + 4 * u;
    const u16* w2h = W2hp + 4 * u;

    for (int t = 0; t < TT; ++t) {
        const float xt = xrow[t];
        // ---- layer-1 gates (rows 2u, 2u+1)
        float a0 = sb1[2 * u]     + xt * sWih1[2 * u];
        float a1 = sb1[2 * u + 1] + xt * sWih1[2 * u + 1];
#pragma unroll 8
        for (int p = 0; p < 128; ++p) {
            ushort4 w  = *(const ushort4*)(w1 + p * 2048);
            float2  hp = *(const float2*)(sh1 + 2 * p);   // broadcast
            a0 += hp.x * bf2f(w.x) + hp.y * bf2f(w.y);
            a1 += hp.x * bf2f(w.z) + hp.y * bf2f(w.w);
        }
        *(float2*)(g + 2 * u) = make_float2(a0, a1);
        __syncthreads();
        // ---- cell 1
        if (u < HD) {
            float gi = g[u], gf = g[HD + u], gg = g[2 * HD + u], go = g[3 * HD + u];
            float ii = 1.f / (1.f + expf(-gi));
            float ff = 1.f / (1.f + expf(-gf));
            float oo = 1.f / (1.f + expf(-go));
            c1 = ff * c1 + ii * tanhf(gg);
            sh1[u] = oo * tanhf(c1);
        }
        __syncthreads();
        // ---- layer-2 gates
        float b0 = sb2[2 * u], b1v = sb2[2 * u + 1];
#pragma unroll 4
        for (int p = 0; p < 128; ++p) {
            ushort4 wi = *(const ushort4*)(w2i + p * 2048);
            ushort4 wh = *(const ushort4*)(w2h + p * 2048);
            float2 h1p = *(const float2*)(sh1 + 2 * p);
            float2 h2p = *(const float2*)(sh2 + 2 * p);
            b0  += h1p.x * bf2f(wi.x) + h1p.y * bf2f(wi.y)
                 + h2p.x * bf2f(wh.x) + h2p.y * bf2f(wh.y);
            b1v += h1p.x * bf2f(wi.z) + h1p.y * bf2f(wi.w)
                 + h2p.x * bf2f(wh.z) + h2p.y * bf2f(wh.w);
        }
        *(float2*)(g + 2 * u) = make_float2(b0, b1v);
        __syncthreads();
        // ---- cell 2 + emit h2
        if (u < HD) {
            float gi = g[u], gf = g[HD + u], gg = g[2 * HD + u], go = g[3 * HD + u];
            float ii = 1.f / (1.f + expf(-gi));
            float ff = 1.f / (1.f + expf(-gf));
            float oo = 1.f / (1.f + expf(-go));
            c2 = ff * c2 + ii * tanhf(gg);
            float h = oo * tanhf(c2);
            sh2[u] = h;
            H2out[(b * TT + t) * HD + u] = f2bf(h);
        }
        __syncthreads();
    }
}

// ---- attention pass A: Y = tanh(H2 @ Wa1^T + ba1), rows = all B*T.
__global__ __launch_bounds__(256) void attn_a_kernel(
    const u16*  __restrict__ Wa1b,   // [256][256] bf16 row-major
    const float* __restrict__ ba1,   // [256]
    const u16*  __restrict__ H2,     // [B*T][256]
    u16*        __restrict__ Y)
{
    __shared__ u16 sW[256 * 258];    // padded stride 258 -> conflict-free b32 reads
    __shared__ float sh[HD];
    const int tid = threadIdx.x;
    for (int i = tid; i < 256 * 256; i += 256) {
        int r = i >> 8, c = i & 255;
        sW[r * 258 + c] = Wa1b[i];
    }
    const float bj = ba1[tid];
    const int row0 = blockIdx.x * 64;
    for (int rr = 0; rr < 64; ++rr) {
        const int row = row0 + rr;
        __syncthreads();                       // sW staged / prev row done
        sh[tid] = bf2f(H2[row * HD + tid]);
        __syncthreads();
        float acc = bj;
        const u16* wrow = sW + tid * 258;
#pragma unroll 8
        for (int k = 0; k < 256; k += 2) {
            u32 w2 = *(const u32*)(wrow + k);
            float2 hp = *(const float2*)(sh + k);
            acc += hp.x * bf2f((u16)(w2 & 0xffffu)) + hp.y * bf2f((u16)(w2 >> 16));
        }
        Y[row * HD + tid] = f2bf(tanhf(acc));
    }
}

// ---- attention pass B: s = Y @ Wa2^T + ba2; softmax over H; out = (attn*h2)@Wo + bo.
__global__ __launch_bounds__(256) void attn_b_kernel(
    const u16*  __restrict__ Wa2b,
    const float* __restrict__ ba2,
    const float* __restrict__ Wo,    // [256]
    const float* __restrict__ bo,    // [1]
    const u16*  __restrict__ H2,
    const u16*  __restrict__ Y,
    float*      __restrict__ out)    // [B*T]
{
    __shared__ u16 sW[256 * 258];
    __shared__ float sy[HD], sh[HD];
    __shared__ float red[8];
    const int tid = threadIdx.x;
    const int lane = tid & 63, wid = tid >> 6;
    for (int i = tid; i < 256 * 256; i += 256) {
        int r = i >> 8, c = i & 255;
        sW[r * 258 + c] = Wa2b[i];
    }
    const float bj  = ba2[tid];
    const float wo  = Wo[tid];
    const float bov = bo[0];
    const int row0 = blockIdx.x * 64;
    for (int rr = 0; rr < 64; ++rr) {
        const int row = row0 + rr;
        __syncthreads();
        sy[tid] = bf2f(Y[row * HD + tid]);
        sh[tid] = bf2f(H2[row * HD + tid]);
        __syncthreads();
        float acc = bj;
        const u16* wrow = sW + tid * 258;
#pragma unroll 8
        for (int k = 0; k < 256; k += 2) {
            u32 w2 = *(const u32*)(wrow + k);
            float2 yp = *(const float2*)(sy + k);
            acc += yp.x * bf2f((u16)(w2 & 0xffffu)) + yp.y * bf2f((u16)(w2 >> 16));
        }
        // block softmax over the 256 columns
        float m = acc;
        for (int off = 32; off >= 1; off >>= 1) m = fmaxf(m, __shfl_xor(m, off));
        if (lane == 0) red[wid] = m;
        __syncthreads();
        m = fmaxf(fmaxf(red[0], red[1]), fmaxf(red[2], red[3]));
        __syncthreads();
        float e = expf(acc - m);
        float s = e;
        for (int off = 32; off >= 1; off >>= 1) s += __shfl_xor(s, off);
        if (lane == 0) red[wid] = s;
        __syncthreads();
        s = red[0] + red[1] + red[2] + red[3];
        __syncthreads();
        float contrib = (e / s) * sh[tid] * wo;
        for (int off = 32; off >= 1; off >>= 1) contrib += __shfl_xor(contrib, off);
        if (lane == 0) red[wid] = contrib;
        __syncthreads();
        if (tid == 0) out[row] = red[0] + red[1] + red[2] + red[3] + bov;
    }
}

extern "C" void kernel_launch(void* const* d_in, const int* in_sizes, int n_in,
                              void* d_out, int out_size, void* d_ws, size_t ws_size,
                              hipStream_t stream) {
    const float* x    = (const float*)d_in[0];
    const float* Wih1 = (const float*)d_in[1];
    const float* bih1 = (const float*)d_in[2];
    const float* Whh1 = (const float*)d_in[3];
    const float* bhh1 = (const float*)d_in[4];
    const float* Wih2 = (const float*)d_in[5];
    const float* bih2 = (const float*)d_in[6];
    const float* Whh2 = (const float*)d_in[7];
    const float* bhh2 = (const float*)d_in[8];
    const float* Wa1  = (const float*)d_in[9];
    const float* ba1  = (const float*)d_in[10];
    const float* Wa2  = (const float*)d_in[11];
    const float* ba2  = (const float*)d_in[12];
    const float* Wo   = (const float*)d_in[13];
    const float* bo   = (const float*)d_in[14];

    char* ws = (char*)d_ws;
    u16*   W1p   = (u16*)(ws + 0);                 // 512 KB
    u16*   W2ip  = (u16*)(ws + 524288);            // 512 KB
    u16*   W2hp  = (u16*)(ws + 1048576);           // 512 KB
    u16*   Wa1b  = (u16*)(ws + 1572864);           // 128 KB
    u16*   Wa2b  = (u16*)(ws + 1703936);           // 128 KB
    float* bias1 = (float*)(ws + 1835008);         // 4 KB
    float* bias2 = (float*)(ws + 1839104);         // 4 KB
    u16*   H2    = (u16*)(ws + 2097152);           // 64 MB
    u16*   Y     = (u16*)(ws + 2097152 + 67108864);// 64 MB
    float* out   = (float*)d_out;

    pack_w_kernel<<<1024, 256, 0, stream>>>(Whh1, W1p);
    pack_w_kernel<<<1024, 256, 0, stream>>>(Wih2, W2ip);
    pack_w_kernel<<<1024, 256, 0, stream>>>(Whh2, W2hp);
    cvt_bf_kernel<<<256, 256, 0, stream>>>(Wa1, Wa1b, 65536);
    cvt_bf_kernel<<<256, 256, 0, stream>>>(Wa2, Wa2b, 65536);
    bias_kernel<<<4, 256, 0, stream>>>(bih1, bhh1, bih2, bhh2, bias1, bias2);

    lstm_kernel<<<BB, 512, 0, stream>>>(x, Wih1, bias1, bias2, W1p, W2ip, W2hp, H2);
    attn_a_kernel<<<2048, 256, 0, stream>>>(Wa1b, ba1, H2, Y);
    attn_b_kernel<<<2048, 256, 0, stream>>>(Wa2b, ba2, Wo, bo, H2, Y, out);
}